// Round 3
// baseline (191.973 us; speedup 1.0000x reference)
//
#include <hip/hip_runtime.h>
#include <math.h>

// Problem constants
constexpr int Bn   = 32;
constexpr int L    = 65536;            // T*K
constexpr int NCH  = 6;
constexpr int SPAN = 256;              // hexads (l-steps) per wave-span
constexpr int NS   = L / SPAN;         // 256 spans per batch row
constexpr int NIT  = SPAN / 64;        // 4 blocks of 64 per span
constexpr int ROW  = L * NCH;          // floats per row (imu/mn/out)
constexpr int EPW_ROW = (L - 1) * NCH; // floats per row (eps_walk)
constexpr int NWAVE = Bn * NS;         // 8192 wave-spans
constexpr float AF = 0.99999f;         // a = 1 - theta*dt (fp32, matches ref)
constexpr float DS_ACC  = 0.2f   * 0.004472135954999579f; // std*sqrt(2*theta*dt)
constexpr float DS_GYRO = 0.015f * 0.004472135954999579f;

// native 2-float vector usable with __builtin_nontemporal_* (HIP float2 is a
// class type, which the builtin rejects)
typedef float vf2 __attribute__((ext_vector_type(2)));

// a^(lane+1) and a^(63-lane), double-accurate, computed once per thread
__device__ __forceinline__ void lane_pows(int lane, float& ap1, float& arev) {
    const double a = (double)AF;
    double t = a, p1 = 1.0, pr = 1.0;
    int e1 = lane + 1, er = 63 - lane;
    #pragma unroll
    for (int k = 0; k < 7; ++k) {
        if (e1 & (1 << k)) p1 *= t;
        if (er & (1 << k)) pr *= t;
        t *= t;
    }
    ap1 = (float)p1; arev = (float)pr;
}

__device__ __forceinline__ float a_pow64() {
    double t = (double)AF;
    #pragma unroll
    for (int k = 0; k < 6; ++k) t *= t;   // a^64
    return (float)t;
}

// load one hexad of scaled innovation x[6] for step l (handles l==0 seed)
__device__ __forceinline__ void load_x(const float* __restrict__ epw,
                                       const float* __restrict__ eps0,
                                       int b, int l, float x[6]) {
    int lm1 = (l == 0) ? 0 : l - 1;                 // clamp (safe addr)
    const vf2* p = (const vf2*)(epw + (size_t)b * EPW_ROW + (size_t)lm1 * NCH);
    vf2 v0 = p[0], v1 = p[1], v2 = p[2];
    x[0] = v0.x * DS_ACC;  x[1] = v0.y * DS_ACC;  x[2] = v1.x * DS_ACC;
    x[3] = v1.y * DS_GYRO; x[4] = v2.x * DS_GYRO; x[5] = v2.y * DS_GYRO;
    if (l == 0) {                                   // bias0 seed = eps0*std0
        const float* e0 = eps0 + b * NCH;
        x[0] = e0[0] * 0.2f;   x[1] = e0[1] * 0.2f;   x[2] = e0[2] * 0.2f;
        x[3] = e0[3] * 0.015f; x[4] = e0[4] * 0.015f; x[5] = e0[5] * 0.015f;
    }
}

// ---------- K1: per-span weighted aggregates ----------
// P_s = sum_t a^(63-t) * [ Horner over it with A64 of x(it,t) ]
// launch_bounds(256,4): allow up to 128 VGPRs so the hoisted loads actually
// stay in registers (round-1 regression: heuristic clamped to 32 VGPR and
// spilled ~5 values/thread to scratch -> +10MB WRITE_SIZE).
__global__ __launch_bounds__(256, 4) void k_partials(
    const float* __restrict__ eps0,
    const float* __restrict__ epw,
    float* __restrict__ part)
{
    int lane = threadIdx.x & 63;
    int w = blockIdx.x * 4 + (threadIdx.x >> 6);   // wave-span id
    int b = w / NS, s = w % NS;

    float ap1, arev; lane_pows(lane, ap1, arev);
    const float A64 = a_pow64();
    int l0 = s * SPAN;

    // hoist ALL loads (independent addresses -> one vmcnt wait)
    float x[NIT][6];
    #pragma unroll
    for (int it = 0; it < NIT; ++it)
        load_x(epw, eps0, b, l0 + it * 64 + lane, x[it]);

    float v[6];
    #pragma unroll
    for (int c = 0; c < 6; ++c) {
        float h = x[0][c];
        #pragma unroll
        for (int it = 1; it < NIT; ++it) h = fmaf(A64, h, x[it][c]);
        v[c] = arev * h;
    }

    #pragma unroll
    for (int c = 0; c < 6; ++c) {
        #pragma unroll
        for (int m = 1; m < 64; m <<= 1) v[c] += __shfl_xor(v[c], m, 64);
    }

    if (lane < 6) {
        float r = v[0];
        if (lane == 1) r = v[1]; else if (lane == 2) r = v[2];
        else if (lane == 3) r = v[3]; else if (lane == 4) r = v[4];
        else if (lane == 5) r = v[5];
        part[(size_t)w * NCH + lane] = r;
    }
}

// ---------- K2: scan span aggregates per chain (tiny, double) ----------
__global__ __launch_bounds__(64) void k_scan(
    const float* __restrict__ part,
    float* __restrict__ carry)
{
    int lane = threadIdx.x;
    int chain = blockIdx.x;              // b*6 + c
    int b = chain / NCH, c = chain % NCH;

    double a = (double)AF;
    double A = a;
    #pragma unroll
    for (int k = 0; k < 8; ++k) A *= A;  // a^256 = a^SPAN
    double A4 = A * A; A4 *= A4;         // A^4 (per-lane span of 4 segments)

    int s0 = lane * 4;
    size_t base = (size_t)b * NS * NCH + c;
    float pv[4];
    #pragma unroll
    for (int k = 0; k < 4; ++k) pv[k] = part[base + (size_t)(s0 + k) * NCH];

    double t = 0.0;
    #pragma unroll
    for (int k = 0; k < 4; ++k) t = A * t + (double)pv[k];

    double I = t, m = A4;
    #pragma unroll
    for (int d = 1; d <= 32; d <<= 1) {
        double up = __shfl_up(I, d, 64);
        if (lane >= d) I = m * up + I;
        m = m * m;
    }
    double cin = __shfl_up(I, 1, 64);
    if (lane == 0) cin = 0.0;

    double e = cin;
    #pragma unroll
    for (int k = 0; k < 4; ++k) {
        carry[base + (size_t)(s0 + k) * NCH] = (float)e;  // E_{s-1}
        e = A * e + (double)pv[k];
    }
}

// ---------- K3: fused scan + elementwise ----------
// Fat-wave structure: ALL loads (epw + carry + imu + mn) issued up front
// (~42 VMEM ops in flight), temp/sin computed while they fly, then 24
// independent Kogge-Stone chains, carry fixup, combine, store.
// launch_bounds(256,4) -> up to 128 VGPRs (need ~95).
__global__ __launch_bounds__(256, 4) void k_apply(
    const float* __restrict__ imu,
    const float* __restrict__ eps0,
    const float* __restrict__ epw,
    const float* __restrict__ mn,
    const float* __restrict__ carry,
    float* __restrict__ out)
{
    int lane = threadIdx.x & 63;
    int w = blockIdx.x * 4 + (threadIdx.x >> 6);
    int b = w / NS, s = w % NS;

    int l0 = s * SPAN;

    // ---- issue ALL global loads up front ----
    float x[NIT][6];
    #pragma unroll
    for (int it = 0; it < NIT; ++it)
        load_x(epw, eps0, b, l0 + it * 64 + lane, x[it]);

    float e[6];
    #pragma unroll
    for (int c = 0; c < 6; ++c) e[c] = carry[(size_t)w * NCH + c];

    vf2 iv[NIT][3], mv[NIT][3];
    #pragma unroll
    for (int it = 0; it < NIT; ++it) {
        int l = l0 + it * 64 + lane;
        size_t roff = (size_t)b * ROW + (size_t)l * NCH;
        const vf2* ip = (const vf2*)(imu + roff);
        const vf2* mp = (const vf2*)(mn + roff);
        #pragma unroll
        for (int q = 0; q < 3; ++q) {
            iv[it][q] = __builtin_nontemporal_load(ip + q);
            mv[it][q] = __builtin_nontemporal_load(mp + q);
        }
    }

    // ---- VALU work that needs no loads: lane powers + temp curve ----
    float ap1, arev; lane_pows(lane, ap1, arev);
    const float A64 = a_pow64();
    const float inv   = 1.0f / 65535.0f;
    const float twopi = 6.283185307179586f;
    float ta[NIT], tg[NIT];
    #pragma unroll
    for (int it = 0; it < NIT; ++it) {
        int l = l0 + it * 64 + lane;
        float tt = (float)l * inv;
        float temp = fmaf(5.0f, __sinf(twopi * tt), fmaf(2.0f, tt, 20.0f));
        ta[it] = temp * 0.001f; tg[it] = temp * 0.01f;
    }

    // ---- 24 independent Kogge-Stone chains, in place ----
    float m = AF;
    #pragma unroll
    for (int d = 1; d < 64; d <<= 1) {
        #pragma unroll
        for (int it = 0; it < NIT; ++it) {
            #pragma unroll
            for (int c = 0; c < 6; ++c) {
                float up = __shfl_up(x[it][c], d, 64);
                if (lane >= d) x[it][c] = fmaf(m, up, x[it][c]);
            }
        }
        m *= m;
    }

    // carry fixup: bias(it) = ap1*e(it) + S(it); e(it+1) = A64*e(it) + S(it)@63
    #pragma unroll
    for (int c = 0; c < 6; ++c) {
        float ec = e[c];
        #pragma unroll
        for (int it = 0; it < NIT; ++it) {
            float z = __shfl(x[it][c], 63, 64);
            x[it][c] = fmaf(ap1, ec, x[it][c]);   // x now holds bias
            ec = fmaf(A64, ec, z);
        }
    }

    // ---- combine + store (non-temporal; out is write-once) ----
    #pragma unroll
    for (int it = 0; it < NIT; ++it) {
        int l = l0 + it * 64 + lane;
        size_t roff = (size_t)b * ROW + (size_t)l * NCH;
        vf2* op = (vf2*)(out + roff);
        vf2 o0, o1, o2;
        o0.x = iv[it][0].x + x[it][0] + mv[it][0].x * 0.1f  + ta[it];
        o0.y = iv[it][0].y + x[it][1] + mv[it][0].y * 0.1f  + ta[it];
        o1.x = iv[it][1].x + x[it][2] + mv[it][1].x * 0.1f  + ta[it];
        o1.y = iv[it][1].y + x[it][3] + mv[it][1].y * 0.01f + tg[it];
        o2.x = iv[it][2].x + x[it][4] + mv[it][2].x * 0.01f + tg[it];
        o2.y = iv[it][2].y + x[it][5] + mv[it][2].y * 0.01f + tg[it];
        __builtin_nontemporal_store(o0, op + 0);
        __builtin_nontemporal_store(o1, op + 1);
        __builtin_nontemporal_store(o2, op + 2);
    }
}

extern "C" void kernel_launch(void* const* d_in, const int* in_sizes, int n_in,
                              void* d_out, int out_size, void* d_ws, size_t ws_size,
                              hipStream_t stream) {
    const float* imu  = (const float*)d_in[0];   // [B, L, 6]
    const float* eps0 = (const float*)d_in[1];   // [B, 6]
    const float* epw  = (const float*)d_in[2];   // [B, L-1, 6]
    const float* mn   = (const float*)d_in[3];   // [B, L, 6]
    float* out = (float*)d_out;

    float* part  = (float*)d_ws;                 // NWAVE*6 floats
    float* carry = part + (size_t)NWAVE * NCH;   // NWAVE*6 floats

    k_partials<<<NWAVE / 4, 256, 0, stream>>>(eps0, epw, part);
    k_scan<<<Bn * NCH, 64, 0, stream>>>(part, carry);
    k_apply<<<NWAVE / 4, 256, 0, stream>>>(imu, eps0, epw, mn, carry, out);
}

// Round 4
// 179.412 us; speedup vs baseline: 1.0700x; 1.0700x over previous
//
#include <hip/hip_runtime.h>
#include <math.h>

// Problem constants
constexpr int Bn   = 32;
constexpr int L    = 65536;            // T*K
constexpr int NCH  = 6;
constexpr int SPAN = 256;              // hexads (l-steps) per wave-span
constexpr int NS   = L / SPAN;         // 256 spans per batch row
constexpr int NIT  = SPAN / 64;        // 4 blocks of 64 per span
constexpr int ROW  = L * NCH;          // floats per row (imu/mn/out)
constexpr int EPW_ROW = (L - 1) * NCH; // floats per row (eps_walk)
constexpr int NWAVE = Bn * NS;         // 8192 wave-spans
constexpr float AF = 0.99999f;         // a = 1 - theta*dt (fp32, matches ref)
constexpr float DS_ACC  = 0.2f   * 0.004472135954999579f; // std*sqrt(2*theta*dt)
constexpr float DS_GYRO = 0.015f * 0.004472135954999579f;

// native clang vectors (HIP float2/float4 are class types -> nontemporal
// builtins reject them)
typedef float vf2 __attribute__((ext_vector_type(2)));
typedef float vf4 __attribute__((ext_vector_type(4)));

// a^(lane+1) and a^(63-lane), double-accurate, computed once per thread
__device__ __forceinline__ void lane_pows(int lane, float& ap1, float& arev) {
    const double a = (double)AF;
    double t = a, p1 = 1.0, pr = 1.0;
    int e1 = lane + 1, er = 63 - lane;
    #pragma unroll
    for (int k = 0; k < 7; ++k) {
        if (e1 & (1 << k)) p1 *= t;
        if (er & (1 << k)) pr *= t;
        t *= t;
    }
    ap1 = (float)p1; arev = (float)pr;
}

__device__ __forceinline__ float a_pow64() {
    double t = (double)AF;
    #pragma unroll
    for (int k = 0; k < 6; ++k) t *= t;   // a^64
    return (float)t;
}

// load one hexad of scaled innovation x[6] for step l (handles l==0 seed)
__device__ __forceinline__ void load_x(const float* __restrict__ epw,
                                       const float* __restrict__ eps0,
                                       int b, int l, float x[6]) {
    int lm1 = (l == 0) ? 0 : l - 1;                 // clamp (safe addr)
    const vf2* p = (const vf2*)(epw + (size_t)b * EPW_ROW + (size_t)lm1 * NCH);
    vf2 v0 = p[0], v1 = p[1], v2 = p[2];
    x[0] = v0.x * DS_ACC;  x[1] = v0.y * DS_ACC;  x[2] = v1.x * DS_ACC;
    x[3] = v1.y * DS_GYRO; x[4] = v2.x * DS_GYRO; x[5] = v2.y * DS_GYRO;
    if (l == 0) {                                   // bias0 seed = eps0*std0
        const float* e0 = eps0 + b * NCH;
        x[0] = e0[0] * 0.2f;   x[1] = e0[1] * 0.2f;   x[2] = e0[2] * 0.2f;
        x[3] = e0[3] * 0.015f; x[4] = e0[4] * 0.015f; x[5] = e0[5] * 0.015f;
    }
}

// ---------- K1: per-span weighted aggregates ----------
__global__ __launch_bounds__(256, 4) void k_partials(
    const float* __restrict__ eps0,
    const float* __restrict__ epw,
    float* __restrict__ part)
{
    int lane = threadIdx.x & 63;
    int w = blockIdx.x * 4 + (threadIdx.x >> 6);   // wave-span id
    int b = w / NS, s = w % NS;

    int l0 = s * SPAN;

    // hoist ALL loads; sched_barrier pins them (round-3: scheduler sank them)
    float x[NIT][6];
    #pragma unroll
    for (int it = 0; it < NIT; ++it)
        load_x(epw, eps0, b, l0 + it * 64 + lane, x[it]);
    __builtin_amdgcn_sched_barrier(0);

    float ap1, arev; lane_pows(lane, ap1, arev);
    const float A64 = a_pow64();

    float v[6];
    #pragma unroll
    for (int c = 0; c < 6; ++c) {
        float h = x[0][c];
        #pragma unroll
        for (int it = 1; it < NIT; ++it) h = fmaf(A64, h, x[it][c]);
        v[c] = arev * h;
    }

    #pragma unroll
    for (int c = 0; c < 6; ++c) {
        #pragma unroll
        for (int m = 1; m < 64; m <<= 1) v[c] += __shfl_xor(v[c], m, 64);
    }

    if (lane < 6) {
        float r = v[0];
        if (lane == 1) r = v[1]; else if (lane == 2) r = v[2];
        else if (lane == 3) r = v[3]; else if (lane == 4) r = v[4];
        else if (lane == 5) r = v[5];
        part[(size_t)w * NCH + lane] = r;
    }
}

// ---------- K2: scan span aggregates per chain (tiny, double) ----------
__global__ __launch_bounds__(64) void k_scan(
    const float* __restrict__ part,
    float* __restrict__ carry)
{
    int lane = threadIdx.x;
    int chain = blockIdx.x;              // b*6 + c
    int b = chain / NCH, c = chain % NCH;

    double a = (double)AF;
    double A = a;
    #pragma unroll
    for (int k = 0; k < 8; ++k) A *= A;  // a^256 = a^SPAN
    double A4 = A * A; A4 *= A4;         // A^4 (per-lane span of 4 segments)

    int s0 = lane * 4;
    size_t base = (size_t)b * NS * NCH + c;
    float pv[4];
    #pragma unroll
    for (int k = 0; k < 4; ++k) pv[k] = part[base + (size_t)(s0 + k) * NCH];

    double t = 0.0;
    #pragma unroll
    for (int k = 0; k < 4; ++k) t = A * t + (double)pv[k];

    double I = t, m = A4;
    #pragma unroll
    for (int d = 1; d <= 32; d <<= 1) {
        double up = __shfl_up(I, d, 64);
        if (lane >= d) I = m * up + I;
        m = m * m;
    }
    double cin = __shfl_up(I, 1, 64);
    if (lane == 0) cin = 0.0;

    double e = cin;
    #pragma unroll
    for (int k = 0; k < 4; ++k) {
        carry[base + (size_t)(s0 + k) * NCH] = (float)e;  // E_{s-1}
        e = A * e + (double)pv[k];
    }
}

// ---------- K3: fused scan + elementwise ----------
// All imu/mn/out traffic at 16 B/lane: a wave-span's region is 6144 B =
// 384 float4 = exactly 6 float4/lane. Bias (per time,ch layout) is
// redistributed to the float4 domain through a wave-PRIVATE LDS tile
// (no __syncthreads: same-wave RAW ordered by lgkmcnt). Stores are
// full-line nt float4 (round-3's 8B nt stores caused ~1.5x write
// amplification: WRITE_SIZE 74MB vs 50MB ideal).
__global__ __launch_bounds__(256, 4) void k_apply(
    const float* __restrict__ imu,
    const float* __restrict__ eps0,
    const float* __restrict__ epw,
    const float* __restrict__ mn,
    const float* __restrict__ carry,
    float* __restrict__ out)
{
    __shared__ float lds[4 * SPAN * NCH];     // 4 waves x 1536 floats = 24 KB
    int lane = threadIdx.x & 63;
    int wv   = threadIdx.x >> 6;
    int w = blockIdx.x * 4 + wv;
    int b = w / NS, s = w % NS;
    int l0 = s * SPAN;
    float* lw = lds + wv * (SPAN * NCH);      // this wave's 1536-float tile

    // ---- phase A: issue epw + carry loads, pinned ----
    float e[6];
    #pragma unroll
    for (int c = 0; c < 6; ++c) e[c] = carry[(size_t)w * NCH + c];
    float x[NIT][6];
    #pragma unroll
    for (int it = 0; it < NIT; ++it)
        load_x(epw, eps0, b, l0 + it * 64 + lane, x[it]);
    __builtin_amdgcn_sched_barrier(0);

    // ---- phase B: issue imu/mn float4 nt loads, pinned ----
    size_t fbase = (size_t)b * ROW + (size_t)l0 * NCH;
    const vf4* ip = (const vf4*)(imu + fbase);
    const vf4* mp = (const vf4*)(mn + fbase);
    vf4 iv[6], mv[6];
    #pragma unroll
    for (int q = 0; q < 6; ++q) {
        iv[q] = __builtin_nontemporal_load(ip + q * 64 + lane);
        mv[q] = __builtin_nontemporal_load(mp + q * 64 + lane);
    }
    __builtin_amdgcn_sched_barrier(0);

    // ---- phase C: VALU while loads fly ----
    float ap1, arev; lane_pows(lane, ap1, arev);
    const float A64 = a_pow64();
    const float inv   = 1.0f / 65535.0f;
    const float twopi = 6.283185307179586f;
    float ta[NIT], tg[NIT];
    #pragma unroll
    for (int it = 0; it < NIT; ++it) {
        int l = l0 + it * 64 + lane;
        float tt = (float)l * inv;
        float temp = fmaf(5.0f, __sinf(twopi * tt), fmaf(2.0f, tt, 20.0f));
        ta[it] = temp * 0.001f; tg[it] = temp * 0.01f;
    }

    // ---- phase D: 24 independent Kogge-Stone chains (waits on epw) ----
    float m = AF;
    #pragma unroll
    for (int d = 1; d < 64; d <<= 1) {
        #pragma unroll
        for (int it = 0; it < NIT; ++it) {
            #pragma unroll
            for (int c = 0; c < 6; ++c) {
                float up = __shfl_up(x[it][c], d, 64);
                if (lane >= d) x[it][c] = fmaf(m, up, x[it][c]);
            }
        }
        m *= m;
    }

    // carry fixup + fold temp term in (per time,ch domain)
    #pragma unroll
    for (int c = 0; c < 6; ++c) {
        float ec = e[c];
        float tc0 = (c < 3) ? 1.0f : 0.0f;    // selects ta vs tg below
        #pragma unroll
        for (int it = 0; it < NIT; ++it) {
            float z = __shfl(x[it][c], 63, 64);
            float t = (c < 3) ? ta[it] : tg[it];
            x[it][c] = fmaf(ap1, ec, x[it][c]) + t;   // bias + temp*tc
            ec = fmaf(A64, ec, z);
        }
        (void)tc0;
    }

    // ---- phase E: write per-lane hexads to the wave tile ----
    #pragma unroll
    for (int it = 0; it < NIT; ++it) {
        vf2* d = (vf2*)(lw + it * 384 + lane * 6);
        vf2 a0 = {x[it][0], x[it][1]};
        vf2 a1 = {x[it][2], x[it][3]};
        vf2 a2 = {x[it][4], x[it][5]};
        d[0] = a0; d[1] = a1; d[2] = a2;
    }

    // ---- phase F: read tile as float4, combine, full-line nt stores ----
    // component channels of float4 j: c = (4j)%6.. -> pattern by j%3:
    // j%3==0: {0,1,2,3} -> ns {.1,.1,.1,.01}
    // j%3==1: {4,5,0,1} -> ns {.01,.01,.1,.1}
    // j%3==2: {2,3,4,5} -> ns {.1,.01,.01,.01}
    int lane3 = lane % 3;                     // (q*64+lane)%3 == (q+lane)%3
    vf4* op = (vf4*)(out + fbase);
    const vf4* lr = (const vf4*)lw;
    #pragma unroll
    for (int q = 0; q < 6; ++q) {
        vf4 v = lr[q * 64 + lane];            // lgkmcnt-ordered vs phase E
        int r = lane3 + (q % 3); if (r >= 3) r -= 3;
        vf4 ns = (r == 0) ? (vf4){0.1f, 0.1f, 0.1f, 0.01f}
               : (r == 1) ? (vf4){0.01f, 0.01f, 0.1f, 0.1f}
                          : (vf4){0.1f, 0.01f, 0.01f, 0.01f};
        vf4 o = iv[q] + v + mv[q] * ns;
        __builtin_nontemporal_store(o, op + q * 64 + lane);
    }
}

extern "C" void kernel_launch(void* const* d_in, const int* in_sizes, int n_in,
                              void* d_out, int out_size, void* d_ws, size_t ws_size,
                              hipStream_t stream) {
    const float* imu  = (const float*)d_in[0];   // [B, L, 6]
    const float* eps0 = (const float*)d_in[1];   // [B, 6]
    const float* epw  = (const float*)d_in[2];   // [B, L-1, 6]
    const float* mn   = (const float*)d_in[3];   // [B, L, 6]
    float* out = (float*)d_out;

    float* part  = (float*)d_ws;                 // NWAVE*6 floats
    float* carry = part + (size_t)NWAVE * NCH;   // NWAVE*6 floats

    k_partials<<<NWAVE / 4, 256, 0, stream>>>(eps0, epw, part);
    k_scan<<<Bn * NCH, 64, 0, stream>>>(part, carry);
    k_apply<<<NWAVE / 4, 256, 0, stream>>>(imu, eps0, epw, mn, carry, out);
}